// Round 13
// baseline (234.954 us; speedup 1.0000x reference)
//
#include <hip/hip_runtime.h>
#include <hip/hip_bf16.h>

// R12: ABLATION ROUND. phaseB pinned at ~43us across all access-pattern
// variants (R8 channel=null, R9 bytes fixed/time not, R11 pipeline=null);
// VALU 7%, occ = exact 2-block/CU 2-round signature, per-block ~22us with
// <8K cycles of accountable work. Split phaseB into B1(replay+raw dump) and
// B2(emit ct+tg from raw) to localize the sink via per-dispatch timing.
// Committed prediction: B1 38-42us / B2 8-12us (replay is sink); if reversed,
// the emit path owned it all along. Overhead ~+8us accepted for the info.

#define N_NODES 100000
#define N_EDGES 1600000
#define N_HOPS 3
#define D_HID 256
#define N_GRAPHS 64

#define CHUNK 32
#define NCHUNK 3125          /* 100000/32 */
#define FG 512               /* fused grid */

#define NB 625               /* node buckets */
#define RB 160               /* nodes per bucket (5 chunks) */
#define SGRID 500            /* scatter blocks, one clean round (2/CU wave-cap) */
#define SB 1024              /* scatter block threads (16 waves) */
#define I4PB 2400            /* int4 edge-groups per block: 500*2400*4 = 4.8M edges */
#define NI4H 400000          /* int4 groups per hop */
#define STAGE_W 11475        /* 9600 records + 3*625 max pad, u32 words */
#define RSTRIDE 11840        /* words per block slice = 47360B = 185*256B */

// ws layout (ws >= 256MiB):
//  [0, 12.8MB)        ct bf16 A-frag [NCHUNK][4][64][8]
//    overlay (prep+scatter only): batch_u8 [100000]
//  [12.8MB, 36.5MB)   records u32 [SGRID][RSTRIDE] = 23.68MB (phase A/B)
//    overlay: s_part bf16 [FG][64*256] = 16.8MB              (fused onward)
//  [36.5MB, 37.8MB)   offs u32 [SGRID][NB] = 1.25MB          (phase A/B)
//  [40MB, ...)        tg_rep f32[64][64] | s_sum f32[16384] | w1p bf16[32768]
//  [45MB, 70.6MB)     tbuf f32 [NB][160*64] = 25.6MB         (B1 -> B2 only)
#define CT_OFF    0u
#define BU8_OFF   0u
#define REC_OFF   12800000u
#define SPART_OFF REC_OFF
#define OFFS_OFF  36500000u
#define SMALL_OFF 40000000u
#define TGR_OFF   SMALL_OFF              /* 64*64*4 = 16384 B */
#define SSUM_OFF  (SMALL_OFF + 32768u)
#define W1P_OFF   (SMALL_OFF + 131072u)
#define TBUF_OFF  45000000u

typedef __attribute__((ext_vector_type(4))) float f32x4;
typedef __attribute__((ext_vector_type(8))) short s16x8;
typedef __attribute__((ext_vector_type(4))) int i32x4;
typedef __attribute__((ext_vector_type(4))) float fv4;

__device__ __forceinline__ unsigned short f2bf_rne(float f) {
    union { float f; unsigned u; } v; v.f = f;
    unsigned r = v.u + 0x7FFFu + ((v.u >> 16) & 1u);
    return (unsigned short)(r >> 16);
}
__device__ __forceinline__ float bf2f(unsigned short s) {
    union { float f; unsigned u; } v; v.u = ((unsigned)s) << 16;
    return v.f;
}
__device__ __forceinline__ unsigned pk_rne(float lo, float hi) {
    return ((unsigned)f2bf_rne(hi) << 16) | (unsigned)f2bf_rne(lo);
}

// ---- Prep: blocks 0-15 pack W1 MFMA-B fragments; blocks 16-113 build u8 batch.
__global__ __launch_bounds__(256) void prep_kernel(const float* __restrict__ w1,
                                                   unsigned short* __restrict__ w1p,
                                                   const int* __restrict__ batch,
                                                   unsigned char* __restrict__ bu8) {
    if (blockIdx.x < 16) {
        int f = blockIdx.x * 256 + threadIdx.x;   // 0..4095
        int t = f >> 4, fr = f & 15, nt = fr >> 2, ks = fr & 3;
        int w = t >> 6, l = t & 63, q = l >> 4, c = l & 15;
        s16x8 v;
#pragma unroll
        for (int j = 0; j < 8; j++)
            v[j] = (short)f2bf_rne(w1[(size_t)(32 * ks + 8 * q + j) * 256 + w * 64 + 16 * nt + c]);
        *(s16x8*)&w1p[(size_t)f * 8] = v;
    } else {
        int i = (blockIdx.x - 16) * 1024 + threadIdx.x * 4;
        if (i < N_NODES) {
            int4 v = *(const int4*)&batch[i];
            uchar4 o;
            o.x = (unsigned char)v.x; o.y = (unsigned char)v.y;
            o.z = (unsigned char)v.z; o.w = (unsigned char)v.w;
            *(uchar4*)&bu8[i] = o;
        }
    }
}

// ---- Phase A: bin edges into bucket-sorted per-block record slices.
__global__ __launch_bounds__(SB) void scatter_kernel(
    const int* __restrict__ ei, const float* __restrict__ ew,
    const unsigned char* __restrict__ bu8, const float* __restrict__ pw,
    unsigned* __restrict__ offs, unsigned* __restrict__ records) {
    __shared__ unsigned cnt[NB], lbase[NB], ccnt[NB];
    __shared__ unsigned wtot[16];
    __shared__ unsigned tot;
    __shared__ unsigned stage[STAGE_W];
    const int tid = threadIdx.x;
    const int lane = tid & 63, wid = tid >> 6;
    const int i40 = blockIdx.x * I4PB;

    if (tid < NB) cnt[tid] = 0u;
    __syncthreads();

    const float pw1 = pw[1], pw2 = pw[2], pw3 = pw[3];

    unsigned rec[12], bkt[12];
#pragma unroll
    for (int k = 0; k < 3; k++) {
        int idx = tid + k * SB;
        if (idx < I4PB) {
            int i4 = i40 + idx;
            unsigned hop = (unsigned)i4 / NI4H;
            int r4 = i4 - (int)hop * NI4H;
            const i32x4* sp4 = (const i32x4*)(ei + (size_t)hop * 2 * N_EDGES);
            i32x4 s = __builtin_nontemporal_load(sp4 + r4);
            i32x4 d = __builtin_nontemporal_load(sp4 + NI4H + r4);
            fv4 wv = __builtin_nontemporal_load((const fv4*)(ew + (size_t)hop * N_EDGES) + r4);
            float pwh = hop == 0 ? pw1 : (hop == 1 ? pw2 : pw3);
#pragma unroll
            for (int j = 0; j < 4; j++) {
                unsigned b = (unsigned)s[j] / RB;
                bkt[k * 4 + j] = b;
                rec[k * 4 + j] = ((unsigned)f2bf_rne(pwh * wv[j]) << 16) |
                                 (unsigned)(((unsigned)s[j] - b * RB) * 64 + (unsigned)bu8[d[j]]);
                atomicAdd(&cnt[b], 1u);
            }
        } else {
#pragma unroll
            for (int j = 0; j < 4; j++) bkt[k * 4 + j] = 0xFFFFFFFFu;
        }
    }
    __syncthreads();

    // per-bucket padded count + block-local prefix sum (NO global atomics)
    unsigned pcv = 0;
    if (tid < NB) {
        unsigned cc = cnt[tid];
        ccnt[tid] = cc;
        pcv = (cc + 3u) & ~3u;
        cnt[tid] = 0u;  // reuse as placement counter
    }
    // inclusive scan of pcv within each wave
    unsigned inc = pcv;
#pragma unroll
    for (int d = 1; d < 64; d <<= 1) {
        unsigned u = __shfl_up(inc, d, 64);
        if (lane >= d) inc += u;
    }
    if (lane == 63) wtot[wid] = inc;
    __syncthreads();
    if (tid < 16) {
        unsigned wv = wtot[tid];
        unsigned winc = wv;
#pragma unroll
        for (int d = 1; d < 16; d <<= 1) {
            unsigned u = __shfl_up(winc, d, 16);
            if ((tid & 15) >= d) winc += u;
        }
        wtot[tid] = winc - wv;  // exclusive wave offset
    }
    __syncthreads();
    if (tid < NB) {
        unsigned lb = inc - pcv + wtot[wid];  // exclusive prefix
        lbase[tid] = lb;
        offs[(size_t)blockIdx.x * NB + tid] = (pcv << 16) | lb;
        if (tid == NB - 1) tot = lb + pcv;
        for (unsigned i = ccnt[tid]; i < pcv; i++) stage[lb + i] = 0u;
    }
    __syncthreads();

#pragma unroll
    for (int k = 0; k < 12; k++) {
        if (bkt[k] != 0xFFFFFFFFu) {
            unsigned o = atomicAdd(&cnt[bkt[k]], 1u);
            stage[lbase[bkt[k]] + o] = rec[k];
        }
    }
    __syncthreads();

    unsigned total = tot;
    unsigned* dst = records + (size_t)blockIdx.x * RSTRIDE;
    for (unsigned i = tid * 4; i < total; i += SB * 4) {
        *(uint4*)&dst[i] = *(const uint4*)&stage[i];
    }
}

// ---- Phase B1 (replay): zero tile, pw0 term, R9-grouped replay, raw dump.
__global__ __launch_bounds__(512) void phaseB_replay_kernel(
    const int* __restrict__ batch, const float* __restrict__ pw,
    const unsigned* __restrict__ offs, const unsigned* __restrict__ records,
    float* __restrict__ tbuf) {
    __shared__ float tile[RB * 65];
    const int tid = threadIdx.x;
    const int b = blockIdx.x;
    const int grp = tid >> 3, gl = tid & 7;

    for (int i = tid; i < RB * 65; i += 512) tile[i] = 0.f;
    __syncthreads();

    if (tid < RB) atomicAdd(&tile[tid * 65 + batch[b * RB + tid]], pw[0]);

    for (int t = grp; t < SGRID; t += 64) {
        unsigned w = offs[(size_t)t * NB + b];
        const unsigned* rp = records + (size_t)t * RSTRIDE + (w & 0xFFFFu);
        unsigned pc = w >> 16;
        for (unsigned base = 4u * gl; base < pc; base += 32u) {
            uint4 r4 = *(const uint4*)(rp + base);
            unsigned m0 = r4.x & 0x3FFFu, m1 = r4.y & 0x3FFFu;
            unsigned m2 = r4.z & 0x3FFFu, m3 = r4.w & 0x3FFFu;
            atomicAdd(&tile[m0 + (m0 >> 6)], bf2f((unsigned short)(r4.x >> 16)));
            atomicAdd(&tile[m1 + (m1 >> 6)], bf2f((unsigned short)(r4.y >> 16)));
            atomicAdd(&tile[m2 + (m2 >> 6)], bf2f((unsigned short)(r4.z >> 16)));
            atomicAdd(&tile[m3 + (m3 >> 6)], bf2f((unsigned short)(r4.w >> 16)));
        }
    }
    __syncthreads();

    // raw dump: f32 [160][64], fully coalesced (5 float4s per thread)
    float* dst = tbuf + (size_t)b * 10240;
    for (int i = tid; i < 2560; i += 512) {
        int r = i >> 4, c4 = (i & 15) * 4;
        f32x4 v;
        v[0] = tile[r * 65 + c4];
        v[1] = tile[r * 65 + c4 + 1];
        v[2] = tile[r * 65 + c4 + 2];
        v[3] = tile[r * 65 + c4 + 3];
        *(f32x4*)&dst[i * 4] = v;
    }
}

// ---- Phase B2 (emit): reload tile, emit ct (MFMA-A bf16 layout) + tg replicas.
__global__ __launch_bounds__(512) void phaseB_emit_kernel(
    const float* __restrict__ tbuf,
    unsigned short* __restrict__ ct, float* __restrict__ tgr) {
    __shared__ float tile[RB * 68];
    const int tid = threadIdx.x;
    const int b = blockIdx.x;

    const float* src = tbuf + (size_t)b * 10240;
    for (int i = tid; i < 2560; i += 512) {
        f32x4 v = *(const f32x4*)&src[i * 4];
        int r = i >> 4, c4 = (i & 15) * 4;
        *(f32x4*)&tile[r * 68 + c4] = v;
    }
    __syncthreads();

    if (tid < 256) {
        const int gt = tid >> 6, l = tid & 63, q = l >> 4, c = l & 15;
        for (int cc = 0; cc < 5; cc++) {
            s16x8 v;
#pragma unroll
            for (int j = 0; j < 8; j++)
                v[j] = (short)f2bf_rne(tile[(cc * 32 + 8 * q + j) * 68 + 16 * gt + c]);
            *(s16x8*)&ct[(((size_t)(b * 5 + cc) * 4 + gt) * 64 + l) * 8] = v;
        }
    }
    if (tid < 64) {
        float sum = 0.f;
        for (int s = 0; s < RB; s++) sum += tile[s * 68 + tid];
        atomicAdd(&tgr[(b & 63) * 64 + tid], sum);
    }
}

// ---- Fused MFMA kernel: per 32-node chunk,
//   U = relu(X@W1 + b1)   (W1 frags from w1p, coalesced)
//   S += Ct^T @ U
__global__ __launch_bounds__(256, 2) void fused_kernel(
    const float* __restrict__ x,
    const unsigned short* __restrict__ w1p,
    const float* __restrict__ b1,
    const unsigned short* __restrict__ ct,
    unsigned short* __restrict__ s_part) {

    __shared__ __align__(16) unsigned short Ut[256 * 40];     // 20 KB
    __shared__ __align__(16) unsigned short x_lds[32 * 136];  // 8.7 KB
    __shared__ __align__(16) unsigned short ct_lds[2048];     // 4 KB

    const int tid = threadIdx.x;
    const int w = tid >> 6, l = tid & 63, q = l >> 4, c = l & 15;
    const int wcol = w * 64;
    const int sr = tid >> 3, sk = (tid & 7) * 16;

    // W1 B-fragments: pre-packed, 16 coalesced 16B loads
    s16x8 w1f[4][4];
    {
        const s16x8* wp = (const s16x8*)(w1p + (size_t)tid * 128);
#pragma unroll
        for (int nt = 0; nt < 4; nt++)
#pragma unroll
            for (int ks = 0; ks < 4; ks++)
                w1f[nt][ks] = wp[nt * 4 + ks];
    }

    float bias[4];
#pragma unroll
    for (int nt = 0; nt < 4; nt++) bias[nt] = b1[wcol + 16 * nt + c];

    f32x4 sacc[4][4];
#pragma unroll
    for (int gt = 0; gt < 4; gt++)
#pragma unroll
        for (int nt = 0; nt < 4; nt++) sacc[gt][nt] = (f32x4)0.f;

    uint4 xp0, xp1;
    s16x8 ctp;

#define PREF(CI)                                                              \
    {                                                                         \
        const float4* p = (const float4*)&x[(size_t)((CI) * 32 + sr) * 128 + sk]; \
        float4 v0 = p[0], v1 = p[1], v2 = p[2], v3 = p[3];                    \
        xp0.x = pk_rne(v0.x, v0.y); xp0.y = pk_rne(v0.z, v0.w);               \
        xp0.z = pk_rne(v1.x, v1.y); xp0.w = pk_rne(v1.z, v1.w);               \
        xp1.x = pk_rne(v2.x, v2.y); xp1.y = pk_rne(v2.z, v2.w);               \
        xp1.z = pk_rne(v3.x, v3.y); xp1.w = pk_rne(v3.z, v3.w);               \
        ctp = *(const s16x8*)&ct[(size_t)(CI) * 2048 + tid * 8];              \
    }

    int ci = blockIdx.x;
    if (ci < NCHUNK) PREF(ci);

    for (; ci < NCHUNK; ci += FG) {
        *(uint4*)&x_lds[sr * 136 + sk] = xp0;
        *(uint4*)&x_lds[sr * 136 + sk + 8] = xp1;
        *(s16x8*)&ct_lds[tid * 8] = ctp;
        __syncthreads();

        s16x8 af[2][4], ctf[4];
#pragma unroll
        for (int mt = 0; mt < 2; mt++)
#pragma unroll
            for (int ks = 0; ks < 4; ks++)
                af[mt][ks] = *(const s16x8*)&x_lds[(16 * mt + c) * 136 + 32 * ks + 8 * q];
#pragma unroll
        for (int gt = 0; gt < 4; gt++)
            ctf[gt] = *(const s16x8*)&ct_lds[(gt * 64 + l) * 8];
        __syncthreads();

        if (ci + FG < NCHUNK) PREF(ci + FG);

        f32x4 u[2][4];
#pragma unroll
        for (int mt = 0; mt < 2; mt++)
#pragma unroll
            for (int nt = 0; nt < 4; nt++) {
                f32x4 a; a[0] = a[1] = a[2] = a[3] = bias[nt];
                u[mt][nt] = a;
            }
#pragma unroll
        for (int ks = 0; ks < 4; ks++)
#pragma unroll
            for (int mt = 0; mt < 2; mt++)
#pragma unroll
                for (int nt = 0; nt < 4; nt++)
                    u[mt][nt] = __builtin_amdgcn_mfma_f32_16x16x32_bf16(
                        af[mt][ks], w1f[nt][ks], u[mt][nt], 0, 0, 0);

#pragma unroll
        for (int mt = 0; mt < 2; mt++)
#pragma unroll
            for (int nt = 0; nt < 4; nt++) {
                f32x4 v = u[mt][nt];
                uint2 d;
                d.x = pk_rne(fmaxf(v[0], 0.f), fmaxf(v[1], 0.f));
                d.y = pk_rne(fmaxf(v[2], 0.f), fmaxf(v[3], 0.f));
                *(uint2*)&Ut[(wcol + 16 * nt + c) * 40 + 16 * mt + 4 * q] = d;
            }

#pragma unroll
        for (int nt = 0; nt < 4; nt++) {
            s16x8 uf = *(const s16x8*)&Ut[(wcol + 16 * nt + c) * 40 + 8 * q];
#pragma unroll
            for (int gt = 0; gt < 4; gt++)
                sacc[gt][nt] = __builtin_amdgcn_mfma_f32_16x16x32_bf16(
                    ctf[gt], uf, sacc[gt][nt], 0, 0, 0);
        }
    }
#undef PREF

    unsigned short* my = s_part + (size_t)blockIdx.x * (64 * 256);
#pragma unroll
    for (int gt = 0; gt < 4; gt++)
#pragma unroll
        for (int nt = 0; nt < 4; nt++)
#pragma unroll
            for (int r = 0; r < 4; r++)
                my[(16 * gt + 4 * q + r) * 256 + wcol + 16 * nt + c] =
                    f2bf_rne(sacc[gt][nt][r]);
}

// 256 blocks: element range split 64-wide, FG dim split 4-way for parallelism
__global__ __launch_bounds__(256) void reduce_kernel(const unsigned short* __restrict__ s_part,
                                                     float* __restrict__ s_sum) {
    __shared__ float red[4][64];
    const int l = threadIdx.x & 63, p = threadIdx.x >> 6;
    const int e = blockIdx.x * 64 + l;
    float a0 = 0.f, a1 = 0.f, a2 = 0.f, a3 = 0.f;
    for (int b = p * (FG / 4); b < (p + 1) * (FG / 4); b += 4) {
        a0 += bf2f(s_part[(size_t)(b + 0) * 16384 + e]);
        a1 += bf2f(s_part[(size_t)(b + 1) * 16384 + e]);
        a2 += bf2f(s_part[(size_t)(b + 2) * 16384 + e]);
        a3 += bf2f(s_part[(size_t)(b + 3) * 16384 + e]);
    }
    red[p][l] = (a0 + a1) + (a2 + a3);
    __syncthreads();
    if (p == 0) s_sum[e] = (red[0][l] + red[1][l]) + (red[2][l] + red[3][l]);
}

__global__ void finalize_kernel(const float* __restrict__ s,
                                const float* __restrict__ tgr,
                                const float* __restrict__ w2,
                                const float* __restrict__ b2,
                                float* __restrict__ out) {
    __shared__ float red[128];
    __shared__ float tgs;
    const int g = blockIdx.x;
    const int f = threadIdx.x;

    // reduce the 64 tg replicas for this graph (wave 0)
    if (f < 64) {
        float v = tgr[f * 64 + g];
        for (int off = 32; off; off >>= 1) v += __shfl_down(v, off, 64);
        if (f == 0) tgs = v;
    }
    __syncthreads();

    float acc = tgs * b2[f];
    for (int k = 0; k < D_HID; k++)
        acc += s[(size_t)g * 256 + k] * w2[(size_t)k * 128 + f];

    red[f] = acc;
    __syncthreads();
    for (int off = 64; off > 0; off >>= 1) {
        if (f < off) red[f] = fmaxf(red[f], red[f + off]);
        __syncthreads();
    }
    float mx = red[0];
    __syncthreads();
    red[f] = expf(acc - mx);
    __syncthreads();
    for (int off = 64; off > 0; off >>= 1) {
        if (f < off) red[f] += red[f + off];
        __syncthreads();
    }
    float lse = logf(red[0]);
    out[(size_t)g * 128 + f] = acc - mx - lse;
}

extern "C" void kernel_launch(void* const* d_in, const int* in_sizes, int n_in,
                              void* d_out, int out_size, void* d_ws, size_t ws_size,
                              hipStream_t stream) {
    const float* x     = (const float*)d_in[0];
    const int*   ei    = (const int*)d_in[1];
    const float* ew    = (const float*)d_in[2];
    const int*   batch = (const int*)d_in[3];
    const float* w1    = (const float*)d_in[4];
    const float* b1    = (const float*)d_in[5];
    const float* w2    = (const float*)d_in[6];
    const float* b2    = (const float*)d_in[7];
    const float* pw    = (const float*)d_in[8];
    float* out = (float*)d_out;

    unsigned short* ctp     = (unsigned short*)((char*)d_ws + CT_OFF);
    unsigned char*  bu8     = (unsigned char*)((char*)d_ws + BU8_OFF);
    unsigned*       records = (unsigned*)((char*)d_ws + REC_OFF);
    unsigned short* s_part  = (unsigned short*)((char*)d_ws + SPART_OFF);
    unsigned*       offsp   = (unsigned*)((char*)d_ws + OFFS_OFF);
    float*          tgrp    = (float*)((char*)d_ws + TGR_OFF);
    float*          s_sum   = (float*)((char*)d_ws + SSUM_OFF);
    unsigned short* w1pp    = (unsigned short*)((char*)d_ws + W1P_OFF);
    float*          tbuf    = (float*)((char*)d_ws + TBUF_OFF);

    hipMemsetAsync(tgrp, 0, 64 * 64 * sizeof(float), stream);

    prep_kernel<<<dim3(114), 256, 0, stream>>>(w1, w1pp, batch, bu8);
    scatter_kernel<<<dim3(SGRID), SB, 0, stream>>>(
        ei, ew, bu8, pw, offsp, records);
    phaseB_replay_kernel<<<dim3(NB), 512, 0, stream>>>(batch, pw, offsp, records, tbuf);
    phaseB_emit_kernel<<<dim3(NB), 512, 0, stream>>>(tbuf, ctp, tgrp);
    fused_kernel<<<dim3(FG), 256, 0, stream>>>(x, w1pp, b1, ctp, s_part);
    reduce_kernel<<<dim3(256), 256, 0, stream>>>(s_part, s_sum);
    finalize_kernel<<<dim3(64), 128, 0, stream>>>(s_sum, tgrp, w2, b2, out);
}

// Round 14
// 228.775 us; speedup vs baseline: 1.0270x; 1.0270x over previous
//
#include <hip/hip_runtime.h>
#include <hip/hip_bf16.h>

// R13: ablation verdict — replay owns phaseB (~38 of 49us), emit ~10. New
// theory: schedulable LDS pool is 128KB/CU, so 44032B/block -> EXACTLY 2
// blocks/CU -> forced 2-round schedule (occ 33% signature, dur = 2*T_block).
// Fix: merge emit back (undo ablation) + tile[160][64] UNPADDED = 40960B ->
// 3 blocks/CU -> single round. No-pad is safe: atomic bank = graph&31,
// random -> ~2-way (free); emit 4-way on 16 banks, immaterial.
// Predict phaseB 44->~25us, occ ->~50, total ~205-210. If phaseB stays ~43
// at occ 33: pool theory dead -> fuse phaseB into scatter next.

#define N_NODES 100000
#define N_EDGES 1600000
#define N_HOPS 3
#define D_HID 256
#define N_GRAPHS 64

#define CHUNK 32
#define NCHUNK 3125          /* 100000/32 */
#define FG 512               /* fused grid */

#define NB 625               /* node buckets */
#define RB 160               /* nodes per bucket (5 chunks) */
#define SGRID 500            /* scatter blocks, one clean round (2/CU wave-cap) */
#define SB 1024              /* scatter block threads (16 waves) */
#define I4PB 2400            /* int4 edge-groups per block: 500*2400*4 = 4.8M edges */
#define NI4H 400000          /* int4 groups per hop */
#define STAGE_W 11475        /* 9600 records + 3*625 max pad, u32 words */
#define RSTRIDE 11840        /* words per block slice = 47360B = 185*256B */

// ws layout (ws >= 256MiB):
//  [0, 12.8MB)        ct bf16 A-frag [NCHUNK][4][64][8]
//    overlay (prep+scatter only): batch_u8 [100000]
//  [12.8MB, 36.5MB)   records u32 [SGRID][RSTRIDE] = 23.68MB (phase A/B)
//    overlay: s_part bf16 [FG][64*256] = 16.8MB              (fused onward)
//  [36.5MB, 37.8MB)   offs u32 [SGRID][NB] = 1.25MB          (phase A/B)
//  [40MB, ...)        tg_rep f32[64][64] | s_sum f32[16384] | w1p bf16[32768]
#define CT_OFF    0u
#define BU8_OFF   0u
#define REC_OFF   12800000u
#define SPART_OFF REC_OFF
#define OFFS_OFF  36500000u
#define SMALL_OFF 40000000u
#define TGR_OFF   SMALL_OFF              /* 64*64*4 = 16384 B */
#define SSUM_OFF  (SMALL_OFF + 32768u)
#define W1P_OFF   (SMALL_OFF + 131072u)

typedef __attribute__((ext_vector_type(4))) float f32x4;
typedef __attribute__((ext_vector_type(8))) short s16x8;
typedef __attribute__((ext_vector_type(4))) int i32x4;
typedef __attribute__((ext_vector_type(4))) float fv4;

__device__ __forceinline__ unsigned short f2bf_rne(float f) {
    union { float f; unsigned u; } v; v.f = f;
    unsigned r = v.u + 0x7FFFu + ((v.u >> 16) & 1u);
    return (unsigned short)(r >> 16);
}
__device__ __forceinline__ float bf2f(unsigned short s) {
    union { float f; unsigned u; } v; v.u = ((unsigned)s) << 16;
    return v.f;
}
__device__ __forceinline__ unsigned pk_rne(float lo, float hi) {
    return ((unsigned)f2bf_rne(hi) << 16) | (unsigned)f2bf_rne(lo);
}

// ---- Prep: blocks 0-15 pack W1 MFMA-B fragments; blocks 16-113 build u8 batch.
__global__ __launch_bounds__(256) void prep_kernel(const float* __restrict__ w1,
                                                   unsigned short* __restrict__ w1p,
                                                   const int* __restrict__ batch,
                                                   unsigned char* __restrict__ bu8) {
    if (blockIdx.x < 16) {
        int f = blockIdx.x * 256 + threadIdx.x;   // 0..4095
        int t = f >> 4, fr = f & 15, nt = fr >> 2, ks = fr & 3;
        int w = t >> 6, l = t & 63, q = l >> 4, c = l & 15;
        s16x8 v;
#pragma unroll
        for (int j = 0; j < 8; j++)
            v[j] = (short)f2bf_rne(w1[(size_t)(32 * ks + 8 * q + j) * 256 + w * 64 + 16 * nt + c]);
        *(s16x8*)&w1p[(size_t)f * 8] = v;
    } else {
        int i = (blockIdx.x - 16) * 1024 + threadIdx.x * 4;
        if (i < N_NODES) {
            int4 v = *(const int4*)&batch[i];
            uchar4 o;
            o.x = (unsigned char)v.x; o.y = (unsigned char)v.y;
            o.z = (unsigned char)v.z; o.w = (unsigned char)v.w;
            *(uchar4*)&bu8[i] = o;
        }
    }
}

// ---- Phase A: bin edges into bucket-sorted per-block record slices.
__global__ __launch_bounds__(SB) void scatter_kernel(
    const int* __restrict__ ei, const float* __restrict__ ew,
    const unsigned char* __restrict__ bu8, const float* __restrict__ pw,
    unsigned* __restrict__ offs, unsigned* __restrict__ records) {
    __shared__ unsigned cnt[NB], lbase[NB], ccnt[NB];
    __shared__ unsigned wtot[16];
    __shared__ unsigned tot;
    __shared__ unsigned stage[STAGE_W];
    const int tid = threadIdx.x;
    const int lane = tid & 63, wid = tid >> 6;
    const int i40 = blockIdx.x * I4PB;

    if (tid < NB) cnt[tid] = 0u;
    __syncthreads();

    const float pw1 = pw[1], pw2 = pw[2], pw3 = pw[3];

    unsigned rec[12], bkt[12];
#pragma unroll
    for (int k = 0; k < 3; k++) {
        int idx = tid + k * SB;
        if (idx < I4PB) {
            int i4 = i40 + idx;
            unsigned hop = (unsigned)i4 / NI4H;
            int r4 = i4 - (int)hop * NI4H;
            const i32x4* sp4 = (const i32x4*)(ei + (size_t)hop * 2 * N_EDGES);
            i32x4 s = __builtin_nontemporal_load(sp4 + r4);
            i32x4 d = __builtin_nontemporal_load(sp4 + NI4H + r4);
            fv4 wv = __builtin_nontemporal_load((const fv4*)(ew + (size_t)hop * N_EDGES) + r4);
            float pwh = hop == 0 ? pw1 : (hop == 1 ? pw2 : pw3);
#pragma unroll
            for (int j = 0; j < 4; j++) {
                unsigned b = (unsigned)s[j] / RB;
                bkt[k * 4 + j] = b;
                rec[k * 4 + j] = ((unsigned)f2bf_rne(pwh * wv[j]) << 16) |
                                 (unsigned)(((unsigned)s[j] - b * RB) * 64 + (unsigned)bu8[d[j]]);
                atomicAdd(&cnt[b], 1u);
            }
        } else {
#pragma unroll
            for (int j = 0; j < 4; j++) bkt[k * 4 + j] = 0xFFFFFFFFu;
        }
    }
    __syncthreads();

    // per-bucket padded count + block-local prefix sum (NO global atomics)
    unsigned pcv = 0;
    if (tid < NB) {
        unsigned cc = cnt[tid];
        ccnt[tid] = cc;
        pcv = (cc + 3u) & ~3u;
        cnt[tid] = 0u;  // reuse as placement counter
    }
    // inclusive scan of pcv within each wave
    unsigned inc = pcv;
#pragma unroll
    for (int d = 1; d < 64; d <<= 1) {
        unsigned u = __shfl_up(inc, d, 64);
        if (lane >= d) inc += u;
    }
    if (lane == 63) wtot[wid] = inc;
    __syncthreads();
    if (tid < 16) {
        unsigned wv = wtot[tid];
        unsigned winc = wv;
#pragma unroll
        for (int d = 1; d < 16; d <<= 1) {
            unsigned u = __shfl_up(winc, d, 16);
            if ((tid & 15) >= d) winc += u;
        }
        wtot[tid] = winc - wv;  // exclusive wave offset
    }
    __syncthreads();
    if (tid < NB) {
        unsigned lb = inc - pcv + wtot[wid];  // exclusive prefix
        lbase[tid] = lb;
        offs[(size_t)blockIdx.x * NB + tid] = (pcv << 16) | lb;
        if (tid == NB - 1) tot = lb + pcv;
        for (unsigned i = ccnt[tid]; i < pcv; i++) stage[lb + i] = 0u;
    }
    __syncthreads();

#pragma unroll
    for (int k = 0; k < 12; k++) {
        if (bkt[k] != 0xFFFFFFFFu) {
            unsigned o = atomicAdd(&cnt[bkt[k]], 1u);
            stage[lbase[bkt[k]] + o] = rec[k];
        }
    }
    __syncthreads();

    unsigned total = tot;
    unsigned* dst = records + (size_t)blockIdx.x * RSTRIDE;
    for (unsigned i = tid * 4; i < total; i += SB * 4) {
        *(uint4*)&dst[i] = *(const uint4*)&stage[i];
    }
}

// ---- Phase B: one block per bucket. UNPADDED LDS f32 tile [160][64] = 40960B
// (3 blocks/CU at a 128KB pool -> single round). slot = m directly.
// Grouped replay (R10 best-measured form): 8-lane group per segment, lane j
// reads rp[4j..4j+3] (group = one 128B line); group g walks t=g,g+64,...
// Emits ct (MFMA-A bf16 layout) + per-replica tg sums (block b -> b&63).
__global__ __launch_bounds__(512) void phaseB_kernel(
    const int* __restrict__ batch, const float* __restrict__ pw,
    const unsigned* __restrict__ offs, const unsigned* __restrict__ records,
    unsigned short* __restrict__ ct, float* __restrict__ tgr) {
    __shared__ float tile[RB * 64];   // 40960 B exactly
    const int tid = threadIdx.x;
    const int b = blockIdx.x;
    const int grp = tid >> 3, gl = tid & 7;

    for (int i = tid; i < RB * 64; i += 512) tile[i] = 0.f;
    __syncthreads();

    if (tid < RB) atomicAdd(&tile[tid * 64 + batch[b * RB + tid]], pw[0]);

    for (int t = grp; t < SGRID; t += 64) {
        unsigned w = offs[(size_t)t * NB + b];
        const unsigned* rp = records + (size_t)t * RSTRIDE + (w & 0xFFFFu);
        unsigned pc = w >> 16;
        for (unsigned base = 4u * gl; base < pc; base += 32u) {
            uint4 r4 = *(const uint4*)(rp + base);
            unsigned m0 = r4.x & 0x3FFFu, m1 = r4.y & 0x3FFFu;
            unsigned m2 = r4.z & 0x3FFFu, m3 = r4.w & 0x3FFFu;
            atomicAdd(&tile[m0], bf2f((unsigned short)(r4.x >> 16)));
            atomicAdd(&tile[m1], bf2f((unsigned short)(r4.y >> 16)));
            atomicAdd(&tile[m2], bf2f((unsigned short)(r4.z >> 16)));
            atomicAdd(&tile[m3], bf2f((unsigned short)(r4.w >> 16)));
        }
    }
    __syncthreads();

    if (tid < 256) {
        const int gt = tid >> 6, l = tid & 63, q = l >> 4, c = l & 15;
        for (int cc = 0; cc < 5; cc++) {
            s16x8 v;
#pragma unroll
            for (int j = 0; j < 8; j++)
                v[j] = (short)f2bf_rne(tile[(cc * 32 + 8 * q + j) * 64 + 16 * gt + c]);
            *(s16x8*)&ct[(((size_t)(b * 5 + cc) * 4 + gt) * 64 + l) * 8] = v;
        }
    }
    if (tid < 64) {
        float sum = 0.f;
        for (int s = 0; s < RB; s++) sum += tile[s * 64 + tid];
        atomicAdd(&tgr[(b & 63) * 64 + tid], sum);
    }
}

// ---- Fused MFMA kernel: per 32-node chunk,
//   U = relu(X@W1 + b1)   (W1 frags from w1p, coalesced)
//   S += Ct^T @ U
__global__ __launch_bounds__(256, 2) void fused_kernel(
    const float* __restrict__ x,
    const unsigned short* __restrict__ w1p,
    const float* __restrict__ b1,
    const unsigned short* __restrict__ ct,
    unsigned short* __restrict__ s_part) {

    __shared__ __align__(16) unsigned short Ut[256 * 40];     // 20 KB
    __shared__ __align__(16) unsigned short x_lds[32 * 136];  // 8.7 KB
    __shared__ __align__(16) unsigned short ct_lds[2048];     // 4 KB

    const int tid = threadIdx.x;
    const int w = tid >> 6, l = tid & 63, q = l >> 4, c = l & 15;
    const int wcol = w * 64;
    const int sr = tid >> 3, sk = (tid & 7) * 16;

    // W1 B-fragments: pre-packed, 16 coalesced 16B loads
    s16x8 w1f[4][4];
    {
        const s16x8* wp = (const s16x8*)(w1p + (size_t)tid * 128);
#pragma unroll
        for (int nt = 0; nt < 4; nt++)
#pragma unroll
            for (int ks = 0; ks < 4; ks++)
                w1f[nt][ks] = wp[nt * 4 + ks];
    }

    float bias[4];
#pragma unroll
    for (int nt = 0; nt < 4; nt++) bias[nt] = b1[wcol + 16 * nt + c];

    f32x4 sacc[4][4];
#pragma unroll
    for (int gt = 0; gt < 4; gt++)
#pragma unroll
        for (int nt = 0; nt < 4; nt++) sacc[gt][nt] = (f32x4)0.f;

    uint4 xp0, xp1;
    s16x8 ctp;

#define PREF(CI)                                                              \
    {                                                                         \
        const float4* p = (const float4*)&x[(size_t)((CI) * 32 + sr) * 128 + sk]; \
        float4 v0 = p[0], v1 = p[1], v2 = p[2], v3 = p[3];                    \
        xp0.x = pk_rne(v0.x, v0.y); xp0.y = pk_rne(v0.z, v0.w);               \
        xp0.z = pk_rne(v1.x, v1.y); xp0.w = pk_rne(v1.z, v1.w);               \
        xp1.x = pk_rne(v2.x, v2.y); xp1.y = pk_rne(v2.z, v2.w);               \
        xp1.z = pk_rne(v3.x, v3.y); xp1.w = pk_rne(v3.z, v3.w);               \
        ctp = *(const s16x8*)&ct[(size_t)(CI) * 2048 + tid * 8];              \
    }

    int ci = blockIdx.x;
    if (ci < NCHUNK) PREF(ci);

    for (; ci < NCHUNK; ci += FG) {
        *(uint4*)&x_lds[sr * 136 + sk] = xp0;
        *(uint4*)&x_lds[sr * 136 + sk + 8] = xp1;
        *(s16x8*)&ct_lds[tid * 8] = ctp;
        __syncthreads();

        s16x8 af[2][4], ctf[4];
#pragma unroll
        for (int mt = 0; mt < 2; mt++)
#pragma unroll
            for (int ks = 0; ks < 4; ks++)
                af[mt][ks] = *(const s16x8*)&x_lds[(16 * mt + c) * 136 + 32 * ks + 8 * q];
#pragma unroll
        for (int gt = 0; gt < 4; gt++)
            ctf[gt] = *(const s16x8*)&ct_lds[(gt * 64 + l) * 8];
        __syncthreads();

        if (ci + FG < NCHUNK) PREF(ci + FG);

        f32x4 u[2][4];
#pragma unroll
        for (int mt = 0; mt < 2; mt++)
#pragma unroll
            for (int nt = 0; nt < 4; nt++) {
                f32x4 a; a[0] = a[1] = a[2] = a[3] = bias[nt];
                u[mt][nt] = a;
            }
#pragma unroll
        for (int ks = 0; ks < 4; ks++)
#pragma unroll
            for (int mt = 0; mt < 2; mt++)
#pragma unroll
                for (int nt = 0; nt < 4; nt++)
                    u[mt][nt] = __builtin_amdgcn_mfma_f32_16x16x32_bf16(
                        af[mt][ks], w1f[nt][ks], u[mt][nt], 0, 0, 0);

#pragma unroll
        for (int mt = 0; mt < 2; mt++)
#pragma unroll
            for (int nt = 0; nt < 4; nt++) {
                f32x4 v = u[mt][nt];
                uint2 d;
                d.x = pk_rne(fmaxf(v[0], 0.f), fmaxf(v[1], 0.f));
                d.y = pk_rne(fmaxf(v[2], 0.f), fmaxf(v[3], 0.f));
                *(uint2*)&Ut[(wcol + 16 * nt + c) * 40 + 16 * mt + 4 * q] = d;
            }

#pragma unroll
        for (int nt = 0; nt < 4; nt++) {
            s16x8 uf = *(const s16x8*)&Ut[(wcol + 16 * nt + c) * 40 + 8 * q];
#pragma unroll
            for (int gt = 0; gt < 4; gt++)
                sacc[gt][nt] = __builtin_amdgcn_mfma_f32_16x16x32_bf16(
                    ctf[gt], uf, sacc[gt][nt], 0, 0, 0);
        }
    }
#undef PREF

    unsigned short* my = s_part + (size_t)blockIdx.x * (64 * 256);
#pragma unroll
    for (int gt = 0; gt < 4; gt++)
#pragma unroll
        for (int nt = 0; nt < 4; nt++)
#pragma unroll
            for (int r = 0; r < 4; r++)
                my[(16 * gt + 4 * q + r) * 256 + wcol + 16 * nt + c] =
                    f2bf_rne(sacc[gt][nt][r]);
}

// 256 blocks: element range split 64-wide, FG dim split 4-way for parallelism
__global__ __launch_bounds__(256) void reduce_kernel(const unsigned short* __restrict__ s_part,
                                                     float* __restrict__ s_sum) {
    __shared__ float red[4][64];
    const int l = threadIdx.x & 63, p = threadIdx.x >> 6;
    const int e = blockIdx.x * 64 + l;
    float a0 = 0.f, a1 = 0.f, a2 = 0.f, a3 = 0.f;
    for (int b = p * (FG / 4); b < (p + 1) * (FG / 4); b += 4) {
        a0 += bf2f(s_part[(size_t)(b + 0) * 16384 + e]);
        a1 += bf2f(s_part[(size_t)(b + 1) * 16384 + e]);
        a2 += bf2f(s_part[(size_t)(b + 2) * 16384 + e]);
        a3 += bf2f(s_part[(size_t)(b + 3) * 16384 + e]);
    }
    red[p][l] = (a0 + a1) + (a2 + a3);
    __syncthreads();
    if (p == 0) s_sum[e] = (red[0][l] + red[1][l]) + (red[2][l] + red[3][l]);
}

__global__ void finalize_kernel(const float* __restrict__ s,
                                const float* __restrict__ tgr,
                                const float* __restrict__ w2,
                                const float* __restrict__ b2,
                                float* __restrict__ out) {
    __shared__ float red[128];
    __shared__ float tgs;
    const int g = blockIdx.x;
    const int f = threadIdx.x;

    // reduce the 64 tg replicas for this graph (wave 0)
    if (f < 64) {
        float v = tgr[f * 64 + g];
        for (int off = 32; off; off >>= 1) v += __shfl_down(v, off, 64);
        if (f == 0) tgs = v;
    }
    __syncthreads();

    float acc = tgs * b2[f];
    for (int k = 0; k < D_HID; k++)
        acc += s[(size_t)g * 256 + k] * w2[(size_t)k * 128 + f];

    red[f] = acc;
    __syncthreads();
    for (int off = 64; off > 0; off >>= 1) {
        if (f < off) red[f] = fmaxf(red[f], red[f + off]);
        __syncthreads();
    }
    float mx = red[0];
    __syncthreads();
    red[f] = expf(acc - mx);
    __syncthreads();
    for (int off = 64; off > 0; off >>= 1) {
        if (f < off) red[f] += red[f + off];
        __syncthreads();
    }
    float lse = logf(red[0]);
    out[(size_t)g * 128 + f] = acc - mx - lse;
}

extern "C" void kernel_launch(void* const* d_in, const int* in_sizes, int n_in,
                              void* d_out, int out_size, void* d_ws, size_t ws_size,
                              hipStream_t stream) {
    const float* x     = (const float*)d_in[0];
    const int*   ei    = (const int*)d_in[1];
    const float* ew    = (const float*)d_in[2];
    const int*   batch = (const int*)d_in[3];
    const float* w1    = (const float*)d_in[4];
    const float* b1    = (const float*)d_in[5];
    const float* w2    = (const float*)d_in[6];
    const float* b2    = (const float*)d_in[7];
    const float* pw    = (const float*)d_in[8];
    float* out = (float*)d_out;

    unsigned short* ctp     = (unsigned short*)((char*)d_ws + CT_OFF);
    unsigned char*  bu8     = (unsigned char*)((char*)d_ws + BU8_OFF);
    unsigned*       records = (unsigned*)((char*)d_ws + REC_OFF);
    unsigned short* s_part  = (unsigned short*)((char*)d_ws + SPART_OFF);
    unsigned*       offsp   = (unsigned*)((char*)d_ws + OFFS_OFF);
    float*          tgrp    = (float*)((char*)d_ws + TGR_OFF);
    float*          s_sum   = (float*)((char*)d_ws + SSUM_OFF);
    unsigned short* w1pp    = (unsigned short*)((char*)d_ws + W1P_OFF);

    hipMemsetAsync(tgrp, 0, 64 * 64 * sizeof(float), stream);

    prep_kernel<<<dim3(114), 256, 0, stream>>>(w1, w1pp, batch, bu8);
    scatter_kernel<<<dim3(SGRID), SB, 0, stream>>>(
        ei, ew, bu8, pw, offsp, records);
    phaseB_kernel<<<dim3(NB), 512, 0, stream>>>(batch, pw, offsp, records, ctp, tgrp);
    fused_kernel<<<dim3(FG), 256, 0, stream>>>(x, w1pp, b1, ctp, s_part);
    reduce_kernel<<<dim3(256), 256, 0, stream>>>(s_part, s_sum);
    finalize_kernel<<<dim3(64), 128, 0, stream>>>(s_sum, tgrp, w2, b2, out);
}